// Round 4
// baseline (2257.692 us; speedup 1.0000x reference)
//
#include <hip/hip_runtime.h>
#include <hip/hip_cooperative_groups.h>
#include <stdint.h>

namespace cg = cooperative_groups;

// instant-ngp multilevel hash-grid encoding, MI355X — phase-coherent version.
//
// Bottleneck (round 2 profile): FETCH_SIZE 2.04 GB vs ~50 MB compulsory —
// all 16 tables hot at once vs 4 MB L2/XCD. Fix: cooperative launch, whole
// grid processes one level at a time (grid.sync before levels 6..15), so the
// hot set is a single table that fits one XCD's L2. Results accumulate in
// registers per 4-level group, written as 2x float4 (full 32B sectors, plain
// stores — nontemporal caused ~2.2x write-through amplification).

struct EmbPtrs { const float2* p[16]; };

constexpr int GRID  = 1024;   // 4 blocks/CU * 256 CU -> co-resident (launch_bounds 4 w/SIMD)
constexpr int BLOCK = 256;
constexpr int PPT   = 4;      // 1024*256*4 = 1,048,576 >= B
constexpr int kRes[16] = {16,20,25,32,40,50,64,80,101,128,161,203,256,322,406,512};

template<int RES_, bool HASH_>
__device__ __forceinline__ float2 level_feat(const float2* __restrict__ tab,
                                             float px, float py, float pz)
{
    constexpr uint32_t P1 = 2654435761u, P2 = 805459861u;
    constexpr uint32_t HMASK = (1u << 19) - 1u;

    const float rh = (float)RES_ * 0.5f;
    const float xp = (px + 1.0f) * rh - 0.5f;   // match reference op order
    const float yp = (py + 1.0f) * rh - 0.5f;
    const float zp = (pz + 1.0f) * rh - 0.5f;
    const float fx = floorf(xp), fy = floorf(yp), fz = floorf(zp);
    const int ix = (int)fx, iy = (int)fy, iz = (int)fz;
    const float tx = xp - fx, ty = yp - fy, tz = zp - fz;

    const float wx[2] = {1.0f - tx, tx};
    const float wy[2] = {1.0f - ty, ty};
    const float wz[2] = {1.0f - tz, tz};
    const bool vx[2] = {(ix   >= 0) && (ix   < RES_), (ix+1 >= 0) && (ix+1 < RES_)};
    const bool vy[2] = {(iy   >= 0) && (iy   < RES_), (iy+1 >= 0) && (iy+1 < RES_)};
    const bool vz[2] = {(iz   >= 0) && (iz   < RES_), (iz+1 >= 0) && (iz+1 < RES_)};

    float ax = 0.0f, ay = 0.0f;

    if constexpr (!HASH_) {
        constexpr int r2 = RES_ * RES_;
        const int base = ix + iy * RES_ + iz * r2;
#pragma unroll
        for (int k = 0; k < 2; ++k)
#pragma unroll
        for (int j = 0; j < 2; ++j)
#pragma unroll
        for (int i = 0; i < 2; ++i) {
            const bool v = vx[i] && vy[j] && vz[k];
            const uint32_t idx = v ? (uint32_t)(base + i + j*RES_ + k*r2) : 0u;
            const float w = v ? (wx[i]*wy[j]*wz[k]) : 0.0f;
            const float2 e = tab[idx];
            ax = fmaf(e.x, w, ax);
            ay = fmaf(e.y, w, ay);
        }
    } else {
        const uint32_t hx0 = (uint32_t)ix;
        const uint32_t hy0 = (uint32_t)iy * P1;
        const uint32_t hz0 = (uint32_t)iz * P2;
        const uint32_t hx[2] = {hx0, hx0 + 1u};
        const uint32_t hy[2] = {hy0, hy0 + P1};
        const uint32_t hz[2] = {hz0, hz0 + P2};
#pragma unroll
        for (int k = 0; k < 2; ++k)
#pragma unroll
        for (int j = 0; j < 2; ++j)
#pragma unroll
        for (int i = 0; i < 2; ++i) {
            const bool v = vx[i] && vy[j] && vz[k];
            uint32_t idx = (hx[i] ^ hy[j] ^ hz[k]) & HMASK;
            idx = v ? idx : 0u;
            const float w = v ? (wx[i]*wy[j]*wz[k]) : 0.0f;
            const float2 e = tab[idx];
            ax = fmaf(e.x, w, ax);
            ay = fmaf(e.y, w, ay);
        }
    }
    return make_float2(ax, ay);
}

template<bool COOP>
__global__ __launch_bounds__(BLOCK, 4) void hashenc_kernel(
    const float* __restrict__ x, EmbPtrs embs, float4* __restrict__ out, int n)
{
    const int g = blockIdx.x * BLOCK + threadIdx.x;     // 0 .. 262143
    cg::grid_group grid = cg::this_grid();

    float px[PPT], py[PPT], pz[PPT];
#pragma unroll
    for (int i = 0; i < PPT; ++i) {
        const int p = g + i * (GRID * BLOCK);
        const int q = (p < n) ? p : 0;                  // safe clamp for tail
        px[i] = x[3*q+0];
        py[i] = x[3*q+1];
        pz[i] = x[3*q+2];
    }

    float2 res[PPT][4];   // one 4-level group of results (static indexing only)

    // SYNC only where the table is big enough to matter (levels 0-5 total <2MB).
#define DO_LEVEL(L, SYNC)                                                      \
    {                                                                          \
        if constexpr (COOP && (SYNC)) grid.sync();                             \
        const float2* __restrict__ tab = embs.p[L];                            \
        _Pragma("unroll")                                                      \
        for (int i = 0; i < PPT; ++i)                                          \
            res[i][(L) & 3] = level_feat<kRes[L], ((L) >= 8)>(                 \
                tab, px[i], py[i], pz[i]);                                     \
    }

#define WRITE_GROUP(G)                                                         \
    {                                                                          \
        _Pragma("unroll")                                                      \
        for (int i = 0; i < PPT; ++i) {                                        \
            const int p = g + i * (GRID * BLOCK);                              \
            if (p < n) {                                                       \
                float4* o = (float4*)((char*)out + (size_t)p * 128 + (G) * 32);\
                o[0] = make_float4(res[i][0].x, res[i][0].y,                   \
                                   res[i][1].x, res[i][1].y);                  \
                o[1] = make_float4(res[i][2].x, res[i][2].y,                   \
                                   res[i][3].x, res[i][3].y);                  \
            }                                                                  \
        }                                                                      \
    }

    DO_LEVEL(0,  false) DO_LEVEL(1,  false) DO_LEVEL(2,  false) DO_LEVEL(3,  false)
    WRITE_GROUP(0)
    DO_LEVEL(4,  false) DO_LEVEL(5,  false) DO_LEVEL(6,  true ) DO_LEVEL(7,  true )
    WRITE_GROUP(1)
    DO_LEVEL(8,  true ) DO_LEVEL(9,  true ) DO_LEVEL(10, true ) DO_LEVEL(11, true )
    WRITE_GROUP(2)
    DO_LEVEL(12, true ) DO_LEVEL(13, true ) DO_LEVEL(14, true ) DO_LEVEL(15, true )
    WRITE_GROUP(3)

#undef DO_LEVEL
#undef WRITE_GROUP
}

extern "C" void kernel_launch(void* const* d_in, const int* in_sizes, int n_in,
                              void* d_out, int out_size, void* d_ws, size_t ws_size,
                              hipStream_t stream) {
    const float* x = (const float*)d_in[0];
    EmbPtrs embs;
    for (int l = 0; l < 16; ++l) embs.p[l] = (const float2*)d_in[1 + l];
    int n = in_sizes[0] / 3;          // (B,3) fp32
    float4* out = (float4*)d_out;

    void* args[] = {(void*)&x, (void*)&embs, (void*)&out, (void*)&n};
    hipError_t e = hipLaunchCooperativeKernel((const void*)hashenc_kernel<true>,
                                              dim3(GRID), dim3(BLOCK), args, 0, stream);
    if (e != hipSuccess) {
        // fallback: same kernel without grid syncs (correct, just less L2-coherent)
        hashenc_kernel<false><<<dim3(GRID), dim3(BLOCK), 0, stream>>>(x, embs, out, n);
    }
}

// Round 5
// 681.643 us; speedup vs baseline: 3.3121x; 3.3121x over previous
//
#include <hip/hip_runtime.h>
#include <stdint.h>

// instant-ngp multilevel hash-grid encoding, MI355X — phase-split multi-kernel.
//
// Round-2 (single kernel, all levels): 700 us, FETCH 2.04 GB (16 tables thrash L2).
// Round-4 (cooperative grid.sync phases): FETCH down to 575 MB but 2240 us —
// grid.sync drained the memory pipeline + 32B split writes amplified WRITE 2x.
// This version: phase barriers = kernel boundaries. One kernel for the 8 dense
// levels (8.2 MB of tables, cache-friendly), one kernel PER hash level (4 MB
// table == one XCD L2; full occupancy, no barriers), results staged level-major
// in d_ws (coalesced 8B writes), final merge assembles the output's upper 64B.
// All global writes are >=64B aligned contiguous -> no partial-line RMW.

struct EmbPtrs { const float2* p[16]; };

constexpr int BLOCK = 256;
constexpr int kRes[16] = {16,20,25,32,40,50,64,80,101,128,161,203,256,322,406,512};

template<int RES_, bool HASH_>
__device__ __forceinline__ float2 level_feat(const float2* __restrict__ tab,
                                             float px, float py, float pz)
{
    constexpr uint32_t P1 = 2654435761u, P2 = 805459861u;
    constexpr uint32_t HMASK = (1u << 19) - 1u;

    const float rh = (float)RES_ * 0.5f;
    const float xp = (px + 1.0f) * rh - 0.5f;   // match reference op order
    const float yp = (py + 1.0f) * rh - 0.5f;
    const float zp = (pz + 1.0f) * rh - 0.5f;
    const float fx = floorf(xp), fy = floorf(yp), fz = floorf(zp);
    const int ix = (int)fx, iy = (int)fy, iz = (int)fz;
    const float tx = xp - fx, ty = yp - fy, tz = zp - fz;

    const float wx[2] = {1.0f - tx, tx};
    const float wy[2] = {1.0f - ty, ty};
    const float wz[2] = {1.0f - tz, tz};
    const bool vx[2] = {(ix   >= 0) && (ix   < RES_), (ix+1 >= 0) && (ix+1 < RES_)};
    const bool vy[2] = {(iy   >= 0) && (iy   < RES_), (iy+1 >= 0) && (iy+1 < RES_)};
    const bool vz[2] = {(iz   >= 0) && (iz   < RES_), (iz+1 >= 0) && (iz+1 < RES_)};

    float ax = 0.0f, ay = 0.0f;

    if constexpr (!HASH_) {
        constexpr int r2 = RES_ * RES_;
        const int base = ix + iy * RES_ + iz * r2;
#pragma unroll
        for (int k = 0; k < 2; ++k)
#pragma unroll
        for (int j = 0; j < 2; ++j)
#pragma unroll
        for (int i = 0; i < 2; ++i) {
            const bool v = vx[i] && vy[j] && vz[k];
            const uint32_t idx = v ? (uint32_t)(base + i + j*RES_ + k*r2) : 0u;
            const float w = v ? (wx[i]*wy[j]*wz[k]) : 0.0f;
            const float2 e = tab[idx];
            ax = fmaf(e.x, w, ax);
            ay = fmaf(e.y, w, ay);
        }
    } else {
        const uint32_t hx0 = (uint32_t)ix;
        const uint32_t hy0 = (uint32_t)iy * P1;
        const uint32_t hz0 = (uint32_t)iz * P2;
        const uint32_t hx[2] = {hx0, hx0 + 1u};
        const uint32_t hy[2] = {hy0, hy0 + P1};
        const uint32_t hz[2] = {hz0, hz0 + P2};
#pragma unroll
        for (int k = 0; k < 2; ++k)
#pragma unroll
        for (int j = 0; j < 2; ++j)
#pragma unroll
        for (int i = 0; i < 2; ++i) {
            const bool v = vx[i] && vy[j] && vz[k];
            uint32_t idx = (hx[i] ^ hy[j] ^ hz[k]) & HMASK;
            idx = v ? idx : 0u;
            const float w = v ? (wx[i]*wy[j]*wz[k]) : 0.0f;
            const float2 e = tab[idx];
            ax = fmaf(e.x, w, ax);
            ay = fmaf(e.y, w, ay);
        }
    }
    return make_float2(ax, ay);
}

// ---- Kernel A: dense levels 0-7, writes lower 64B of each point's 128B ----
__global__ __launch_bounds__(BLOCK) void dense_kernel(
    const float* __restrict__ x, EmbPtrs embs, float4* __restrict__ out, int n)
{
    const int b = blockIdx.x * BLOCK + threadIdx.x;
    if (b >= n) return;
    const float px = x[3*b+0], py = x[3*b+1], pz = x[3*b+2];

    float2 f[8];
    f[0] = level_feat<16,false>(embs.p[0], px, py, pz);
    f[1] = level_feat<20,false>(embs.p[1], px, py, pz);
    f[2] = level_feat<25,false>(embs.p[2], px, py, pz);
    f[3] = level_feat<32,false>(embs.p[3], px, py, pz);
    f[4] = level_feat<40,false>(embs.p[4], px, py, pz);
    f[5] = level_feat<50,false>(embs.p[5], px, py, pz);
    f[6] = level_feat<64,false>(embs.p[6], px, py, pz);
    f[7] = level_feat<80,false>(embs.p[7], px, py, pz);

    float4* o = out + (size_t)b * 8;        // 64B aligned-contiguous
#pragma unroll
    for (int i = 0; i < 4; ++i)
        o[i] = make_float4(f[2*i].x, f[2*i].y, f[2*i+1].x, f[2*i+1].y);
}

// ---- One kernel per hash level: 4MB table == one XCD L2; coalesced 8B out ----
template<int L>
__global__ __launch_bounds__(BLOCK) void hash_level_kernel(
    const float* __restrict__ x, const float2* __restrict__ tab,
    float2* __restrict__ ws, int n)
{
    const int b = blockIdx.x * BLOCK + threadIdx.x;
    if (b >= n) return;
    const float px = x[3*b+0], py = x[3*b+1], pz = x[3*b+2];
    ws[b] = level_feat<kRes[L], true>(tab, px, py, pz);
}

// ---- Merge: gather 8 level-major streams -> upper 64B of each point ----
__global__ __launch_bounds__(BLOCK) void merge_kernel(
    const float2* __restrict__ ws, float4* __restrict__ out, int n)
{
    const int b = blockIdx.x * BLOCK + threadIdx.x;
    if (b >= n) return;
    float2 f[8];
#pragma unroll
    for (int l = 0; l < 8; ++l)
        f[l] = ws[(size_t)l * n + b];
    float4* o = out + (size_t)b * 8 + 4;    // 64B aligned-contiguous
#pragma unroll
    for (int i = 0; i < 4; ++i)
        o[i] = make_float4(f[2*i].x, f[2*i].y, f[2*i+1].x, f[2*i+1].y);
}

// ---- Fallback (round-2 single kernel) if d_ws is too small ----
__global__ __launch_bounds__(BLOCK) void fallback_kernel(
    const float* __restrict__ x, EmbPtrs embs, float4* __restrict__ out, int n)
{
    const int b = blockIdx.x * BLOCK + threadIdx.x;
    if (b >= n) return;
    const float px = x[3*b+0], py = x[3*b+1], pz = x[3*b+2];
    float2 f[16];
    f[0]  = level_feat<16, false>(embs.p[0],  px, py, pz);
    f[1]  = level_feat<20, false>(embs.p[1],  px, py, pz);
    f[2]  = level_feat<25, false>(embs.p[2],  px, py, pz);
    f[3]  = level_feat<32, false>(embs.p[3],  px, py, pz);
    f[4]  = level_feat<40, false>(embs.p[4],  px, py, pz);
    f[5]  = level_feat<50, false>(embs.p[5],  px, py, pz);
    f[6]  = level_feat<64, false>(embs.p[6],  px, py, pz);
    f[7]  = level_feat<80, false>(embs.p[7],  px, py, pz);
    f[8]  = level_feat<101,true >(embs.p[8],  px, py, pz);
    f[9]  = level_feat<128,true >(embs.p[9],  px, py, pz);
    f[10] = level_feat<161,true >(embs.p[10], px, py, pz);
    f[11] = level_feat<203,true >(embs.p[11], px, py, pz);
    f[12] = level_feat<256,true >(embs.p[12], px, py, pz);
    f[13] = level_feat<322,true >(embs.p[13], px, py, pz);
    f[14] = level_feat<406,true >(embs.p[14], px, py, pz);
    f[15] = level_feat<512,true >(embs.p[15], px, py, pz);
    float4* o = out + (size_t)b * 8;
#pragma unroll
    for (int i = 0; i < 8; ++i)
        o[i] = make_float4(f[2*i].x, f[2*i].y, f[2*i+1].x, f[2*i+1].y);
}

extern "C" void kernel_launch(void* const* d_in, const int* in_sizes, int n_in,
                              void* d_out, int out_size, void* d_ws, size_t ws_size,
                              hipStream_t stream) {
    const float* x = (const float*)d_in[0];
    EmbPtrs embs;
    for (int l = 0; l < 16; ++l) embs.p[l] = (const float2*)d_in[1 + l];
    const int n = in_sizes[0] / 3;          // (B,3) fp32
    const int grid = (n + BLOCK - 1) / BLOCK;
    float4* out = (float4*)d_out;

    const size_t need = (size_t)8 * (size_t)n * sizeof(float2);   // 64 MB @ n=1M
    if (ws_size >= need) {
        float2* ws = (float2*)d_ws;
        dense_kernel<<<grid, BLOCK, 0, stream>>>(x, embs, out, n);
        hash_level_kernel< 8><<<grid, BLOCK, 0, stream>>>(x, embs.p[ 8], ws + 0*(size_t)n, n);
        hash_level_kernel< 9><<<grid, BLOCK, 0, stream>>>(x, embs.p[ 9], ws + 1*(size_t)n, n);
        hash_level_kernel<10><<<grid, BLOCK, 0, stream>>>(x, embs.p[10], ws + 2*(size_t)n, n);
        hash_level_kernel<11><<<grid, BLOCK, 0, stream>>>(x, embs.p[11], ws + 3*(size_t)n, n);
        hash_level_kernel<12><<<grid, BLOCK, 0, stream>>>(x, embs.p[12], ws + 4*(size_t)n, n);
        hash_level_kernel<13><<<grid, BLOCK, 0, stream>>>(x, embs.p[13], ws + 5*(size_t)n, n);
        hash_level_kernel<14><<<grid, BLOCK, 0, stream>>>(x, embs.p[14], ws + 6*(size_t)n, n);
        hash_level_kernel<15><<<grid, BLOCK, 0, stream>>>(x, embs.p[15], ws + 7*(size_t)n, n);
        merge_kernel<<<grid, BLOCK, 0, stream>>>(ws, out, n);
    } else {
        fallback_kernel<<<grid, BLOCK, 0, stream>>>(x, embs, out, n);
    }
}